// Round 15
// baseline (942.068 us; speedup 1.0000x reference)
//
#include <hip/hip_runtime.h>
#include <hip/hip_bf16.h>

#define T_TASKS 8
#define B_ROWS 4096
#define PADROWS 4352      // 4096 + 256 so partial BM=256 tiles stay in-bounds
#define BM 256
#define BN 256
#define BK 32
#define MAXT256 24        // sum over tasks of ceil(cnt/256) <= 8 + 4096/256 = 24

typedef __attribute__((ext_vector_type(4))) float f32x4;
typedef __attribute__((ext_vector_type(8))) short bf16x8;

#define GLOAD_LDS16(g, l) __builtin_amdgcn_global_load_lds( \
    (const __attribute__((address_space(1))) void*)(g), \
    (__attribute__((address_space(3))) void*)(l), 16, 0, 0)

__device__ __forceinline__ unsigned short f32_to_bf16(float f) {
    union { float f; unsigned int u; } v; v.f = f;
    unsigned int r = v.u + 0x7FFF + ((v.u >> 16) & 1);  // RNE
    return (unsigned short)(r >> 16);
}

__device__ __forceinline__ unsigned int pack2_bf16(float lo, float hi) {
    __hip_bfloat162 h = __float22bfloat162_rn(make_float2(lo, hi));  // lo -> low 16 bits
    union { __hip_bfloat162 h; unsigned int u; } c; c.h = h;
    return c.u;
}

// ---------------- setup: counting sort by task + BM=256 tile table ----------------
__global__ void setup_kernel(const int* __restrict__ task, int* __restrict__ perm,
                             int* __restrict__ offs, int* __restrict__ table) {
    __shared__ int cnt[T_TASKS];
    __shared__ int cur[T_TASKS];
    int tid = threadIdx.x;
    if (tid < T_TASKS) cnt[tid] = 0;
    __syncthreads();
    for (int b = tid; b < B_ROWS; b += blockDim.x)
        atomicAdd(&cnt[task[b]], 1);
    __syncthreads();
    if (tid == 0) {
        int o = 0;
        for (int t = 0; t < T_TASKS; ++t) { offs[t] = o; cur[t] = o; o += cnt[t]; }
        offs[T_TASKS] = o;
        int s = 0;
        for (int t = 0; t < T_TASKS; ++t) {
            int nt = (cnt[t] + BM - 1) / BM;
            for (int j = 0; j < nt; ++j) table[s++] = (t << 16) | j;
        }
        for (; s < MAXT256; ++s) table[s] = -1;
    }
    __syncthreads();
    for (int b = tid; b < B_ROWS; b += blockDim.x) {
        int t = task[b];
        int pos = atomicAdd(&cur[t], 1);
        perm[pos] = b;
    }
}

// ---------------- permute + cast x -> bf16 ----------------
__global__ void permute_cast_kernel(const float* __restrict__ x, const int* __restrict__ perm,
                                    unsigned short* __restrict__ xp) {
    int rowp = blockIdx.x;
    int src = perm[rowp];
    const float4* xin = reinterpret_cast<const float4*>(x + (size_t)src * 1024);
    unsigned short* dst = xp + (size_t)rowp * 1024;
    int c4 = threadIdx.x;
    float4 v = xin[c4];
    ushort4 o;
    o.x = f32_to_bf16(v.x); o.y = f32_to_bf16(v.y);
    o.z = f32_to_bf16(v.z); o.w = f32_to_bf16(v.w);
    *reinterpret_cast<ushort4*>(dst + c4 * 4) = o;
}

// ---------------- VAE reparameterization ----------------
__global__ void vae_kernel(const float* __restrict__ scat, const float* __restrict__ eps,
                           const int* __restrict__ perm, unsigned short* __restrict__ z) {
    int rowp = blockIdx.x;
    int c = threadIdx.x;
    int src = perm[rowp];
    float mu = scat[(size_t)rowp * 512 + c];
    float ls = scat[(size_t)rowp * 512 + 256 + c];
    float e  = eps[(size_t)src * 256 + c];
    z[(size_t)rowp * 256 + c] = f32_to_bf16(mu + __expf(ls) * e);
}

// ---------------- 256x256 grouped GEMM, f32 [K][N] weights consumed directly ----------------
// Rationale (R6-R14 invariant): every config runs at ~8 TB/s total memory-path traffic;
// time tracks traffic. staged bytes ~ M*N*K*(1/BM+1/BN) -> 256^2 tile halves it vs 128^2.
// A: bf16 [rowp][K] grouped (padded), global_load_lds, src chunk XOR ((row>>1)&3), linear LDS.
//    16 lines of 16 rows; wave w stages lines 2w, 2w+1.
// B: f32 [t][K][N] reg-staged (R11 path scaled): thread (bn=tid&255, bc=tid>>8) loads 16
//    k-strided dwords at fixed n (wave = 64 consecutive n -> coalesced 256B), cvt_pk ->
//    2x ds_write_b128 into Bs[n][k] at slots (bc*2+e)^((bn>>1)&3) (uniform banks).
// 8 waves (wr=wave>>1 in 0..3: 64-row band; wc=wave&1: 128-col band), acc[4][8],
// 64 KB dbuf LDS, launch_bounds(512,2) (1 block/CU, VGPR cap 256), XCD-chunked bx remap.
// Loop: load_b(s+1) -> stage_a(s+1) -> compute(s) -> write_b(s+1) -> barrier  (R12-proven).
// MODE 0: relu -> bf16 store; MODE 1: f32 store; MODE 2: sigmoid -> f32 scatter via perm
template<int MODE>
__global__ __launch_bounds__(512, 2)
void gemm256_kernel(const unsigned short* __restrict__ A,
                    const float* __restrict__ W,
                    const float* __restrict__ bias, void* __restrict__ dst,
                    const int* __restrict__ offs, const int* __restrict__ table,
                    const int* __restrict__ perm,
                    int K, int N, int ldd, int Btot, int GX)
{
    __shared__ unsigned short As[2][BM * BK];   // 16 KB each
    __shared__ unsigned short Bs[2][BN * BK];   // 16 KB each  (64 KB total)

    const int bxh = blockIdx.x;
    const int tid = threadIdx.x;

    // XCD-chunked bijective bx remap (GX % 8 == 0 for all launches here)
    int bx = (bxh & 7) * (GX >> 3) + (bxh >> 3);

    int t, mtile, off, cnt;
    if (table != nullptr) {
        int v = table[bx];
        if (v < 0) return;
        t = v >> 16; mtile = v & 0xFFFF;
        off = offs[t]; cnt = offs[t + 1] - off;
    } else {
        t = 0; mtile = bx; off = 0; cnt = Btot;
    }
    const int n0 = blockIdx.y * BN;

    const int lane = tid & 63;
    const int wave = tid >> 6;                  // 0..7
    const int wr = wave >> 1;                   // 0..3: 64-row band
    const int wc = wave & 1;                    // 0..1: 128-col band

    // ---- A staging geometry (R6/R12-proven, 16 lines) ----
    const int rl   = lane >> 2;                 // 0..15 row within 16-row line
    const int csrc = ((lane & 3) ^ ((rl >> 1) & 3)) * 8;
    const unsigned short* Ab = A + ((size_t)(off + mtile * BM + rl)) * K + csrc;

    // ---- B staging geometry: thread -> (n, k-half) ----
    const int bn = tid & 255;                   // 0..255 (col)
    const int bc = tid >> 8;                    // 0..1 -> k rows bc*16..+15
    const float* Wb = W + (size_t)t * K * N + n0 + bn;
    const int swz = (bn >> 1) & 3;
    float br[16];

    auto stage_a = [&](int buf, int k0) {
        #pragma unroll
        for (int jj = 0; jj < 2; ++jj) {
            int j = wave * 2 + jj;              // 0..15: A 16-row line
            GLOAD_LDS16(Ab + (size_t)(j * 16) * K + k0, &As[buf][j * 512]);
        }
    };
    auto load_b = [&](int k0) {
        const float* p = Wb + (size_t)(k0 + bc * 16) * N;
        #pragma unroll
        for (int r = 0; r < 16; ++r)
            br[r] = p[(size_t)r * N];
    };
    auto write_b = [&](int buf) {
        uint4 wv;
        wv.x = pack2_bf16(br[0], br[1]);
        wv.y = pack2_bf16(br[2], br[3]);
        wv.z = pack2_bf16(br[4], br[5]);
        wv.w = pack2_bf16(br[6], br[7]);
        *reinterpret_cast<uint4*>(&Bs[buf][bn * 32 + (((bc * 2) ^ swz) * 8)]) = wv;
        wv.x = pack2_bf16(br[8], br[9]);
        wv.y = pack2_bf16(br[10], br[11]);
        wv.z = pack2_bf16(br[12], br[13]);
        wv.w = pack2_bf16(br[14], br[15]);
        *reinterpret_cast<uint4*>(&Bs[buf][bn * 32 + (((bc * 2 + 1) ^ swz) * 8)]) = wv;
    };

    f32x4 acc[4][8];
    #pragma unroll
    for (int m = 0; m < 4; ++m)
        #pragma unroll
        for (int n = 0; n < 8; ++n)
            acc[m][n] = (f32x4){0.f, 0.f, 0.f, 0.f};

    auto compute = [&](int buf) {
        bf16x8 af[4], bfr[8];
        #pragma unroll
        for (int m = 0; m < 4; ++m) {
            int rf = wr * 64 + m * 16 + (lane & 15);
            af[m] = *reinterpret_cast<const bf16x8*>(
                &As[buf][rf * 32 + (((lane >> 4) ^ ((rf >> 1) & 3)) * 8)]);
        }
        #pragma unroll
        for (int n = 0; n < 8; ++n) {
            int nf = wc * 128 + n * 16 + (lane & 15);
            bfr[n] = *reinterpret_cast<const bf16x8*>(
                &Bs[buf][nf * 32 + (((lane >> 4) ^ ((nf >> 1) & 3)) * 8)]);
        }
        #pragma unroll
        for (int m = 0; m < 4; ++m)
            #pragma unroll
            for (int n = 0; n < 8; ++n)
                acc[m][n] = __builtin_amdgcn_mfma_f32_16x16x32_bf16(af[m], bfr[n], acc[m][n], 0, 0, 0);
    };

    // ---- prologue ----
    const int nsteps = K / BK;
    load_b(0);
    stage_a(0, 0);
    write_b(0);          // compiler waits br via vmcnt; gload_lds drains at barrier
    __syncthreads();

    int cur = 0;
    for (int s = 0; s < nsteps; ++s) {
        if (s + 1 < nsteps) {
            load_b((s + 1) * BK);            // B reg loads first (cvt waits only these)
            stage_a(cur ^ 1, (s + 1) * BK);  // A async -> LDS[next]
        }
        compute(cur);
        if (s + 1 < nsteps) write_b(cur ^ 1);
        __syncthreads();
        cur ^= 1;
    }

    // ---- epilogue ----
    const float* bt = bias + (size_t)t * N;
    #pragma unroll
    for (int n = 0; n < 8; ++n) {
        int col = n0 + wc * 128 + n * 16 + (lane & 15);
        float bv = bt[col];
        #pragma unroll
        for (int m = 0; m < 4; ++m) {
            int rbase = mtile * BM + wr * 64 + m * 16 + ((lane >> 4) << 2);
            #pragma unroll
            for (int j = 0; j < 4; ++j) {
                int local = rbase + j;
                if (local >= cnt) continue;
                float v = acc[m][n][j] + bv;
                if (MODE == 0) {
                    ((unsigned short*)dst)[(size_t)(off + local) * ldd + col] =
                        f32_to_bf16(fmaxf(v, 0.f));
                } else if (MODE == 1) {
                    ((float*)dst)[(size_t)(off + local) * ldd + col] = v;
                } else {
                    int grow = perm[off + local];
                    ((float*)dst)[(size_t)grow * ldd + col] = 1.f / (1.f + __expf(-v));
                }
            }
        }
    }
}

extern "C" void kernel_launch(void* const* d_in, const int* in_sizes, int n_in,
                              void* d_out, int out_size, void* d_ws, size_t ws_size,
                              hipStream_t stream) {
    const float* x      = (const float*)d_in[0];
    const int*   task   = (const int*)d_in[1];
    const float* eps    = (const float*)d_in[2];
    const float* enc_W1 = (const float*)d_in[3];
    const float* enc_b1 = (const float*)d_in[4];
    const float* enc_W2 = (const float*)d_in[5];
    const float* enc_b2 = (const float*)d_in[6];
    const float* enc_W3 = (const float*)d_in[7];
    const float* enc_b3 = (const float*)d_in[8];
    const float* enc_W4 = (const float*)d_in[9];
    const float* enc_b4 = (const float*)d_in[10];
    const float* ds_W1  = (const float*)d_in[11];
    const float* ds_b1  = (const float*)d_in[12];
    const float* ds_W2  = (const float*)d_in[13];
    const float* ds_b2  = (const float*)d_in[14];
    const float* hd_W1  = (const float*)d_in[15];
    const float* hd_b1  = (const float*)d_in[16];
    const float* hd_W2  = (const float*)d_in[17];
    const float* hd_b2  = (const float*)d_in[18];
    float* out = (float*)d_out;

    // ---- workspace layout (~47 MB) ----
    char* ws = (char*)d_ws;
    int* perm  = (int*)ws;
    int* offs  = (int*)(ws + 16384);
    int* table = (int*)(ws + 16384 + 256);
    char* p = ws + 32768;
    unsigned short* xp = (unsigned short*)p; p += (size_t)PADROWS * 1024 * 2;
    unsigned short* h1 = (unsigned short*)p; p += (size_t)PADROWS * 2048 * 2;
    unsigned short* h2 = (unsigned short*)p; p += (size_t)PADROWS * 2048 * 2;
    unsigned short* zb = (unsigned short*)p; p += (size_t)PADROWS * 256 * 2;
    float* scat = out;   // reuse d_out as 8 MB scat scratch; fully overwritten later

    setup_kernel<<<1, 1024, 0, stream>>>(task, perm, offs, table);
    permute_cast_kernel<<<B_ROWS, 256, 0, stream>>>(x, perm, xp);

    // encoder (grouped; GX=24, 24%8==0 for the XCD remap)
    gemm256_kernel<0><<<dim3(MAXT256, 8), 512, 0, stream>>>(xp, enc_W1, enc_b1, h1, offs, table, nullptr, 1024, 2048, 2048, B_ROWS, MAXT256);
    gemm256_kernel<0><<<dim3(MAXT256, 8), 512, 0, stream>>>(h1, enc_W2, enc_b2, h2, offs, table, nullptr, 2048, 2048, 2048, B_ROWS, MAXT256);
    gemm256_kernel<0><<<dim3(MAXT256, 8), 512, 0, stream>>>(h2, enc_W3, enc_b3, h1, offs, table, nullptr, 2048, 2048, 2048, B_ROWS, MAXT256);
    gemm256_kernel<1><<<dim3(MAXT256, 2), 512, 0, stream>>>(h1, enc_W4, enc_b4, scat, offs, table, nullptr, 2048, 512, 512, B_ROWS, MAXT256);

    vae_kernel<<<B_ROWS, 256, 0, stream>>>(scat, eps, perm, zb);

    // decoder shared layers (ungrouped: t=0, all rows; GX=16)
    gemm256_kernel<0><<<dim3(16, 8), 512, 0, stream>>>(zb, ds_W1, ds_b1, h2, nullptr, nullptr, nullptr, 256, 2048, 2048, B_ROWS, 16);
    gemm256_kernel<0><<<dim3(16, 8), 512, 0, stream>>>(h2, ds_W2, ds_b2, h1, nullptr, nullptr, nullptr, 2048, 2048, 2048, B_ROWS, 16);

    // heads (grouped)
    gemm256_kernel<0><<<dim3(MAXT256, 8), 512, 0, stream>>>(h1, hd_W1, hd_b1, h2, offs, table, nullptr, 2048, 2048, 2048, B_ROWS, MAXT256);
    gemm256_kernel<2><<<dim3(MAXT256, 4), 512, 0, stream>>>(h2, hd_W2, hd_b2, out, offs, table, perm, 2048, 1024, 1024, B_ROWS, MAXT256);
}

// Round 16
// 726.814 us; speedup vs baseline: 1.2962x; 1.2962x over previous
//
#include <hip/hip_runtime.h>
#include <hip/hip_bf16.h>

#define T_TASKS 8
#define B_ROWS 4096
#define PADROWS 4352      // +256 so partial BM=256 tiles stay in-bounds
#define MAXT128 40        // BM=128 tiles: 8 + 4096/128
#define MAXT256 24        // BM=256 tiles: 8 + 4096/256

typedef __attribute__((ext_vector_type(4))) float f32x4;
typedef __attribute__((ext_vector_type(8))) short bf16x8;

#define GLOAD_LDS16(g, l) __builtin_amdgcn_global_load_lds( \
    (const __attribute__((address_space(1))) void*)(g), \
    (__attribute__((address_space(3))) void*)(l), 16, 0, 0)

#define WAITV2() asm volatile("s_waitcnt vmcnt(2)" ::: "memory")
#define PBAR()   asm volatile("s_barrier" ::: "memory")

struct TP { const float* src; unsigned short* dst; int K; int N; int ntiles; };

__device__ __forceinline__ unsigned short f32_to_bf16(float f) {
    union { float f; unsigned int u; } v; v.f = f;
    unsigned int r = v.u + 0x7FFF + ((v.u >> 16) & 1);  // RNE
    return (unsigned short)(r >> 16);
}

// ---------------- setup: counting sort + BOTH tile tables (BM=128 and BM=256) -------------
__global__ void setup_kernel(const int* __restrict__ task, int* __restrict__ perm,
                             int* __restrict__ offs, int* __restrict__ table128,
                             int* __restrict__ table256) {
    __shared__ int cnt[T_TASKS];
    __shared__ int cur[T_TASKS];
    int tid = threadIdx.x;
    if (tid < T_TASKS) cnt[tid] = 0;
    __syncthreads();
    for (int b = tid; b < B_ROWS; b += blockDim.x)
        atomicAdd(&cnt[task[b]], 1);
    __syncthreads();
    if (tid == 0) {
        int o = 0;
        for (int t = 0; t < T_TASKS; ++t) { offs[t] = o; cur[t] = o; o += cnt[t]; }
        offs[T_TASKS] = o;
        int s = 0;
        for (int t = 0; t < T_TASKS; ++t) {
            int nt = (cnt[t] + 127) >> 7;
            for (int j = 0; j < nt; ++j) table128[s++] = (t << 16) | j;
        }
        for (; s < MAXT128; ++s) table128[s] = -1;
        s = 0;
        for (int t = 0; t < T_TASKS; ++t) {
            int nt = (cnt[t] + 255) >> 8;
            for (int j = 0; j < nt; ++j) table256[s++] = (t << 16) | j;
        }
        for (; s < MAXT256; ++s) table256[s] = -1;
    }
    __syncthreads();
    for (int b = tid; b < B_ROWS; b += blockDim.x) {
        int t = task[b];
        int pos = atomicAdd(&cur[t], 1);
        perm[pos] = b;
    }
}

// ---------------- permute + cast x -> bf16 ----------------
__global__ void permute_cast_kernel(const float* __restrict__ x, const int* __restrict__ perm,
                                    unsigned short* __restrict__ xp) {
    int rowp = blockIdx.x;
    int src = perm[rowp];
    const float4* xin = reinterpret_cast<const float4*>(x + (size_t)src * 1024);
    unsigned short* dst = xp + (size_t)rowp * 1024;
    int c4 = threadIdx.x;
    float4 v = xin[c4];
    ushort4 o;
    o.x = f32_to_bf16(v.x); o.y = f32_to_bf16(v.y);
    o.z = f32_to_bf16(v.z); o.w = f32_to_bf16(v.w);
    *reinterpret_cast<ushort4*>(dst + c4 * 4) = o;
}

// ---------------- VAE reparameterization ----------------
__global__ void vae_kernel(const float* __restrict__ scat, const float* __restrict__ eps,
                           const int* __restrict__ perm, unsigned short* __restrict__ z) {
    int rowp = blockIdx.x;
    int c = threadIdx.x;
    int src = perm[rowp];
    float mu = scat[(size_t)rowp * 512 + c];
    float ls = scat[(size_t)rowp * 512 + 256 + c];
    float e  = eps[(size_t)src * 256 + c];
    z[(size_t)rowp * 256 + c] = f32_to_bf16(mu + __expf(ls) * e);
}

// ---------------- standalone weight transpose (enc_W1 only) ----------------
__global__ __launch_bounds__(256)
void transpose_cast_kernel(const float* __restrict__ W, unsigned short* __restrict__ Wt,
                           int K, int N) {
    const size_t toff = (size_t)blockIdx.z * K * N;
    const float* Ws = W + toff;
    unsigned short* Wd = Wt + toff;
    const int k0 = blockIdx.x * 64;
    const int n0 = blockIdx.y * 64;
    __shared__ unsigned short Tt[64 * 64];
    const int tid = threadIdx.x;
    const int n = tid & 63;
    const int kq = tid >> 6;
    #pragma unroll
    for (int i = 0; i < 4; ++i) {
        int kk = kq * 16 + i * 4;
        const float* p = Ws + (size_t)(k0 + kk) * N + n0 + n;
        float v0 = p[0];
        float v1 = p[(size_t)N];
        float v2 = p[(size_t)2 * N];
        float v3 = p[(size_t)3 * N];
        unsigned int lo = (unsigned int)f32_to_bf16(v0) | ((unsigned int)f32_to_bf16(v1) << 16);
        unsigned int hi = (unsigned int)f32_to_bf16(v2) | ((unsigned int)f32_to_bf16(v3) << 16);
        int c = (kk >> 2) ^ (n & 15);
        *reinterpret_cast<uint2*>(Tt + n * 64 + c * 4) = make_uint2(lo, hi);
    }
    __syncthreads();
    #pragma unroll
    for (int it = 0; it < 2; ++it) {
        int c  = it * 256 + tid;
        int nn = c >> 3;
        int cg = c & 7;
        int c1 = (cg * 2) ^ (nn & 15);
        int c2 = (cg * 2 + 1) ^ (nn & 15);
        uint2 a = *reinterpret_cast<const uint2*>(Tt + nn * 64 + c1 * 4);
        uint2 b = *reinterpret_cast<const uint2*>(Tt + nn * 64 + c2 * 4);
        uint4 o = make_uint4(a.x, a.y, b.x, b.y);
        *reinterpret_cast<uint4*>(Wd + (size_t)(n0 + nn) * K + k0 + cg * 8) = o;
    }
}

// =================== 8-PHASE 256x256 GEMM (BK=64, 512 thr, 128 KB LDS) ===================
// T3+T4 on the big layers. Tiles T_j (64-K each) computed at phases [4j..4j+3]; buffer
// parity j%2 is dead during [4j+4..4j+7] -> its 4 half-tiles for T_{j+2} are staged exactly
// there, 1 half (2 gload_lds/wave) per phase. vmcnt(2)+s_barrier at tile boundaries
// certifies all earlier stages landed for ALL waves; vmcnt never drains to 0 in the loop.
// Raw s_barrier with "memory" clobber (NOT __syncthreads -> no vmcnt(0) drain).
// Swizzle: 16B slot ^= (row&7) on 8-slot (128 B) rows; staged via per-lane pre-swizzled
// global source (m173), read with the same XOR -> 2-way max.
// Transpose role (bx >= GX): 2 tiles/block (512 threads).
template<int MODE>
__global__ __launch_bounds__(512, 2)
void gemm8p_kernel(const unsigned short* __restrict__ A,
                   const unsigned short* __restrict__ Wt,
                   const float* __restrict__ bias, void* __restrict__ dst,
                   const int* __restrict__ offs, const int* __restrict__ table,
                   const int* __restrict__ perm,
                   int K, int N, int ldd, int Btot, int GX, TP tpa, TP tpb)
{
    __shared__ unsigned short As_[2][256 * 64];   // 32 KB each
    __shared__ unsigned short Bs_[2][256 * 64];   // 32 KB each  (128 KB total)

    const int bxh = blockIdx.x;
    const int tid = threadIdx.x;

    if (bxh >= GX) {
        // ---------- transpose role: 2 tiles per 512-thread block ----------
        int half = tid >> 8;
        int ltid = tid & 255;
        int tile = ((bxh - GX) * gridDim.y + blockIdx.y) * 2 + half;
        unsigned short* Tt = &As_[0][0] + half * 4096;
        const float* src = nullptr; unsigned short* dstp = nullptr; int tK = 64, tN = 64;
        bool act = true;
        if (tile < tpa.ntiles) { src = tpa.src; dstp = tpa.dst; tK = tpa.K; tN = tpa.N; }
        else {
            tile -= tpa.ntiles;
            if (tile >= tpb.ntiles) act = false;
            else { src = tpb.src; dstp = tpb.dst; tK = tpb.K; tN = tpb.N; }
        }
        int k0 = 0, n0 = 0; size_t toff = 0;
        if (act) {
            int tk = tK >> 6, tn = tN >> 6;
            int z = tile / (tk * tn);
            int r = tile % (tk * tn);
            k0 = (r % tk) * 64; n0 = (r / tk) * 64;
            toff = (size_t)z * tK * tN;
        }
        const int n = ltid & 63;
        const int kq = ltid >> 6;
        if (act) {
            const float* Ws = src + toff;
            #pragma unroll
            for (int i = 0; i < 4; ++i) {
                int kk = kq * 16 + i * 4;
                const float* p = Ws + (size_t)(k0 + kk) * tN + n0 + n;
                float v0 = p[0];
                float v1 = p[(size_t)tN];
                float v2 = p[(size_t)2 * tN];
                float v3 = p[(size_t)3 * tN];
                unsigned int lo = (unsigned int)f32_to_bf16(v0) | ((unsigned int)f32_to_bf16(v1) << 16);
                unsigned int hi = (unsigned int)f32_to_bf16(v2) | ((unsigned int)f32_to_bf16(v3) << 16);
                int c = (kk >> 2) ^ (n & 15);
                *reinterpret_cast<uint2*>(Tt + n * 64 + c * 4) = make_uint2(lo, hi);
            }
        }
        __syncthreads();
        if (act) {
            unsigned short* Wd = dstp + toff;
            #pragma unroll
            for (int it = 0; it < 2; ++it) {
                int c  = it * 256 + ltid;
                int nn = c >> 3;
                int cg = c & 7;
                int c1 = (cg * 2) ^ (nn & 15);
                int c2 = (cg * 2 + 1) ^ (nn & 15);
                uint2 a = *reinterpret_cast<const uint2*>(Tt + nn * 64 + c1 * 4);
                uint2 b = *reinterpret_cast<const uint2*>(Tt + nn * 64 + c2 * 4);
                uint4 o = make_uint4(a.x, a.y, b.x, b.y);
                *reinterpret_cast<uint4*>(Wd + (size_t)(n0 + nn) * tK + k0 + cg * 8) = o;
            }
        }
        return;
    }

    // ---------- GEMM role ----------
    int bx = (bxh & 7) * (GX >> 3) + (bxh >> 3);   // GX % 8 == 0 everywhere

    int t, mtile, off, cnt;
    if (table != nullptr) {
        int v = table[bx];
        if (v < 0) return;
        t = v >> 16; mtile = v & 0xFFFF;
        off = offs[t]; cnt = offs[t + 1] - off;
    } else {
        t = 0; mtile = bx; off = 0; cnt = Btot;
    }
    const int n0 = blockIdx.y * 256;

    const int lane = tid & 63;
    const int wave = tid >> 6;                  // 0..7
    const int wm = wave >> 2;                   // 0..1: 128-row band
    const int wn = wave & 3;                    // 0..3: 64-col band

    // per-lane staging source (pre-swizzled: slot ^= row&7; rows %8==0 per instr)
    const int aRow  = lane >> 3;                                // 0..7
    const int aSlot = ((lane & 7) ^ aRow) * 8;                  // bf16 offset of 16B slot
    const unsigned short* Ab = A + ((size_t)(off + mtile * 256 + aRow)) * K + aSlot;
    const unsigned short* Bb = Wt + ((size_t)t * N + n0 + aRow) * K + aSlot;

    const int nt = K >> 6;                      // K-tiles (16 or 32, even)

    auto stA = [&](int c, int h, int kt) {
        int k0 = (kt < nt ? kt : nt - 1) << 6;
        #pragma unroll
        for (int j = 0; j < 2; ++j) {
            int r0 = h * 128 + (wave * 2 + j) * 8;
            GLOAD_LDS16(Ab + (size_t)r0 * K + k0, &As_[c][r0 * 64]);
        }
    };
    auto stB = [&](int c, int h, int kt) {
        int k0 = (kt < nt ? kt : nt - 1) << 6;
        #pragma unroll
        for (int j = 0; j < 2; ++j) {
            int r0 = h * 128 + (wave * 2 + j) * 8;
            GLOAD_LDS16(Bb + (size_t)r0 * K + k0, &Bs_[c][r0 * 64]);
        }
    };

    f32x4 acc[8][4];
    #pragma unroll
    for (int m = 0; m < 8; ++m)
        #pragma unroll
        for (int n = 0; n < 4; ++n)
            acc[m][n] = (f32x4){0.f, 0.f, 0.f, 0.f};

    auto comp = [&](int c, int mg, int kf) {   // 16 MFMA: m-group x n0-3 x kf
        bf16x8 af[4], bfr[4];
        #pragma unroll
        for (int m = 0; m < 4; ++m) {
            int rf = wm * 128 + (mg * 4 + m) * 16 + (lane & 15);
            af[m] = *reinterpret_cast<const bf16x8*>(
                &As_[c][rf * 64 + (((kf * 4 + (lane >> 4)) ^ (rf & 7)) * 8)]);
        }
        #pragma unroll
        for (int n = 0; n < 4; ++n) {
            int nf = wn * 64 + n * 16 + (lane & 15);
            bfr[n] = *reinterpret_cast<const bf16x8*>(
                &Bs_[c][nf * 64 + (((kf * 4 + (lane >> 4)) ^ (nf & 7)) * 8)]);
        }
        #pragma unroll
        for (int m = 0; m < 4; ++m)
            #pragma unroll
            for (int n = 0; n < 4; ++n)
                acc[mg * 4 + m][n] =
                    __builtin_amdgcn_mfma_f32_16x16x32_bf16(af[m], bfr[n], acc[mg * 4 + m][n], 0, 0, 0);
    };

    // ---- prologue: stage T0 (4 halves, 8 gloads/wave) ----
    stB(0, 0, 0); stB(0, 1, 0); stA(0, 0, 0); stA(0, 1, 0);

    // ---- main loop: iteration i computes T_{2i} (buf0) and T_{2i+1} (buf1) ----
    for (int i = 0; i < (nt >> 1); ++i) {
        int T1 = 2 * i + 1, T2 = 2 * i + 2;
        // phases 0-3: compute buf0, stage T1 -> buf1 (dead window of buf1)
        stB(1, 0, T1); WAITV2(); PBAR(); comp(0, 0, 0); PBAR();
        stB(1, 1, T1);           PBAR(); comp(0, 1, 0); PBAR();
        stA(1, 0, T1);           PBAR(); comp(0, 0, 1); PBAR();
        stA(1, 1, T1);           PBAR(); comp(0, 1, 1); PBAR();
        // phases 4-7: compute buf1, stage T2 -> buf0 (dead window of buf0)
        stB(0, 0, T2); WAITV2(); PBAR(); comp(1, 0, 0); PBAR();
        stB(0, 1, T2);           PBAR(); comp(1, 1, 0); PBAR();
        stA(0, 0, T2);           PBAR(); comp(1, 0, 1); PBAR();
        stA(0, 1, T2);           PBAR(); comp(1, 1, 1); PBAR();
    }

    // ---- epilogue ----
    const float* bt = bias + (size_t)t * N;
    #pragma unroll
    for (int mi = 0; mi < 8; ++mi) {
        int rbase = mtile * 256 + wm * 128 + mi * 16 + ((lane >> 4) << 2);
        #pragma unroll
        for (int n = 0; n < 4; ++n) {
            int col = n0 + wn * 64 + n * 16 + (lane & 15);
            float bv = bt[col];
            #pragma unroll
            for (int j = 0; j < 4; ++j) {
                int local = rbase + j;
                if (local >= cnt) continue;
                float v = acc[mi][n][j] + bv;
                if (MODE == 0) {
                    ((unsigned short*)dst)[(size_t)(off + local) * ldd + col] =
                        f32_to_bf16(fmaxf(v, 0.f));
                } else if (MODE == 1) {
                    ((float*)dst)[(size_t)(off + local) * ldd + col] = v;
                } else {
                    int grow = perm[off + local];
                    ((float*)dst)[(size_t)grow * ldd + col] = 1.f / (1.f + __expf(-v));
                }
            }
        }
    }
}

// =================== R12 gemm12 (BM=128, templated BN) for small layers ===================
template<int MODE, int BN>
__global__ __launch_bounds__(256, (BN == 64 ? 6 : 4))
void gemm12_kernel(const unsigned short* __restrict__ A,
                   const unsigned short* __restrict__ Wt,
                   const float* __restrict__ bias, void* __restrict__ dst,
                   const int* __restrict__ offs, const int* __restrict__ table,
                   const int* __restrict__ perm,
                   int K, int N, int ldd, int Btot, int GX, TP tpa, TP tpb)
{
    constexpr int BM = 128, BK = 32;
    constexpr int NR = BN / 32;
    __shared__ unsigned short As[2][BM * BK];
    __shared__ unsigned short Bs[2][BN * BK];

    const int bxh = blockIdx.x;
    const int tid = threadIdx.x;

    if (bxh >= GX) {
        // ---------- transpose role (1 tile / 256-thread block) ----------
        int tile = (bxh - GX) * gridDim.y + blockIdx.y;
        const float* src; unsigned short* dstp; int tK, tN;
        if (tile < tpa.ntiles) { src = tpa.src; dstp = tpa.dst; tK = tpa.K; tN = tpa.N; }
        else {
            tile -= tpa.ntiles;
            if (tile >= tpb.ntiles) return;
            src = tpb.src; dstp = tpb.dst; tK = tpb.K; tN = tpb.N;
        }
        int tk = tK >> 6, tn = tN >> 6;
        int z = tile / (tk * tn);
        int r = tile % (tk * tn);
        int k0 = (r % tk) * 64, n0 = (r / tk) * 64;
        const size_t toff = (size_t)z * tK * tN;
        const float* Ws = src + toff;
        unsigned short* Wd = dstp + toff;
        unsigned short* Tt = &As[0][0];
        const int n = tid & 63;
        const int kq = tid >> 6;
        #pragma unroll
        for (int i = 0; i < 4; ++i) {
            int kk = kq * 16 + i * 4;
            const float* p = Ws + (size_t)(k0 + kk) * tN + n0 + n;
            float v0 = p[0];
            float v1 = p[(size_t)tN];
            float v2 = p[(size_t)2 * tN];
            float v3 = p[(size_t)3 * tN];
            unsigned int lo = (unsigned int)f32_to_bf16(v0) | ((unsigned int)f32_to_bf16(v1) << 16);
            unsigned int hi = (unsigned int)f32_to_bf16(v2) | ((unsigned int)f32_to_bf16(v3) << 16);
            int c = (kk >> 2) ^ (n & 15);
            *reinterpret_cast<uint2*>(Tt + n * 64 + c * 4) = make_uint2(lo, hi);
        }
        __syncthreads();
        #pragma unroll
        for (int it = 0; it < 2; ++it) {
            int c  = it * 256 + tid;
            int nn = c >> 3;
            int cg = c & 7;
            int c1 = (cg * 2) ^ (nn & 15);
            int c2 = (cg * 2 + 1) ^ (nn & 15);
            uint2 a = *reinterpret_cast<const uint2*>(Tt + nn * 64 + c1 * 4);
            uint2 b = *reinterpret_cast<const uint2*>(Tt + nn * 64 + c2 * 4);
            uint4 o = make_uint4(a.x, a.y, b.x, b.y);
            *reinterpret_cast<uint4*>(Wd + (size_t)(n0 + nn) * tK + k0 + cg * 8) = o;
        }
        return;
    }

    // ---------- GEMM role ----------
    int bx = (bxh & 7) * (GX >> 3) + (bxh >> 3);

    int t, mtile, off, cnt;
    if (table != nullptr) {
        int v = table[bx];
        if (v < 0) return;
        t = v >> 16; mtile = v & 0xFFFF;
        off = offs[t]; cnt = offs[t + 1] - off;
    } else {
        t = 0; mtile = bx; off = 0; cnt = Btot;
    }
    const int n0 = blockIdx.y * BN;

    const int lane = tid & 63;
    const int wave = tid >> 6;
    const int wr = wave >> 1, wc = wave & 1;

    const int rl   = lane >> 2;
    const int csrc = ((lane & 3) ^ ((rl >> 1) & 3)) * 8;
    const unsigned short* Ab = A + ((size_t)(off + mtile * BM + rl)) * K + csrc;
    const unsigned short* Bb = Wt + ((size_t)t * N + n0 + rl) * K + csrc;

    auto stage = [&](int buf, int k0) {
        #pragma unroll
        for (int jj = 0; jj < 2; ++jj) {
            int j = wave * 2 + jj;
            GLOAD_LDS16(Ab + (size_t)(j * 16) * K + k0, &As[buf][j * 512]);
        }
        #pragma unroll
        for (int jb = 0; jb < BN / 64; ++jb) {
            int j = wave * (BN / 64) + jb;
            GLOAD_LDS16(Bb + (size_t)(j * 16) * K + k0, &Bs[buf][j * 512]);
        }
    };

    f32x4 acc[4][NR];
    #pragma unroll
    for (int m = 0; m < 4; ++m)
        #pragma unroll
        for (int n = 0; n < NR; ++n)
            acc[m][n] = (f32x4){0.f, 0.f, 0.f, 0.f};

    auto compute = [&](int buf) {
        bf16x8 af[4], bfr[NR];
        #pragma unroll
        for (int m = 0; m < 4; ++m) {
            int rf = wr * 64 + m * 16 + (lane & 15);
            af[m] = *reinterpret_cast<const bf16x8*>(
                &As[buf][rf * 32 + (((lane >> 4) ^ ((rf >> 1) & 3)) * 8)]);
        }
        #pragma unroll
        for (int n = 0; n < NR; ++n) {
            int nf = wc * (BN / 2) + n * 16 + (lane & 15);
            bfr[n] = *reinterpret_cast<const bf16x8*>(
                &Bs[buf][nf * 32 + (((lane >> 4) ^ ((nf >> 1) & 3)) * 8)]);
        }
        #pragma unroll
        for (int m = 0; m < 4; ++m)
            #pragma unroll
            for (int n = 0; n < NR; ++n)
                acc[m][n] = __builtin_amdgcn_mfma_f32_16x16x32_bf16(af[m], bfr[n], acc[m][n], 0, 0, 0);
    };

    const int nsteps = K / BK;
    stage(0, 0);
    __syncthreads();
    int cur = 0;
    for (int s = 0; s < nsteps; ++s) {
        if (s + 1 < nsteps) stage(cur ^ 1, (s + 1) * BK);
        compute(cur);
        __syncthreads();
        cur ^= 1;
    }

    const float* bt = bias + (size_t)t * N;
    #pragma unroll
    for (int n = 0; n < NR; ++n) {
        int col = n0 + wc * (BN / 2) + n * 16 + (lane & 15);
        float bv = bt[col];
        #pragma unroll
        for (int m = 0; m < 4; ++m) {
            int rbase = mtile * BM + wr * 64 + m * 16 + ((lane >> 4) << 2);
            #pragma unroll
            for (int j = 0; j < 4; ++j) {
                int local = rbase + j;
                if (local >= cnt) continue;
                float v = acc[m][n][j] + bv;
                if (MODE == 0) {
                    ((unsigned short*)dst)[(size_t)(off + local) * ldd + col] =
                        f32_to_bf16(fmaxf(v, 0.f));
                } else if (MODE == 1) {
                    ((float*)dst)[(size_t)(off + local) * ldd + col] = v;
                } else {
                    int grow = perm[off + local];
                    ((float*)dst)[(size_t)grow * ldd + col] = 1.f / (1.f + __expf(-v));
                }
            }
        }
    }
}

extern "C" void kernel_launch(void* const* d_in, const int* in_sizes, int n_in,
                              void* d_out, int out_size, void* d_ws, size_t ws_size,
                              hipStream_t stream) {
    const float* x      = (const float*)d_in[0];
    const int*   task   = (const int*)d_in[1];
    const float* eps    = (const float*)d_in[2];
    const float* enc_W1 = (const float*)d_in[3];
    const float* enc_b1 = (const float*)d_in[4];
    const float* enc_W2 = (const float*)d_in[5];
    const float* enc_b2 = (const float*)d_in[6];
    const float* enc_W3 = (const float*)d_in[7];
    const float* enc_b3 = (const float*)d_in[8];
    const float* enc_W4 = (const float*)d_in[9];
    const float* enc_b4 = (const float*)d_in[10];
    const float* ds_W1  = (const float*)d_in[11];
    const float* ds_b1  = (const float*)d_in[12];
    const float* ds_W2  = (const float*)d_in[13];
    const float* ds_b2  = (const float*)d_in[14];
    const float* hd_W1  = (const float*)d_in[15];
    const float* hd_b1  = (const float*)d_in[16];
    const float* hd_W2  = (const float*)d_in[17];
    const float* hd_b2  = (const float*)d_in[18];
    float* out = (float*)d_out;

    // ---- workspace layout (~365 MB) ----
    char* ws = (char*)d_ws;
    int* perm     = (int*)ws;
    int* offs     = (int*)(ws + 16384);
    int* table128 = (int*)(ws + 16384 + 256);
    int* table256 = (int*)(ws + 16384 + 512);
    char* p = ws + 32768;
    unsigned short* xp = (unsigned short*)p; p += (size_t)PADROWS * 1024 * 2;
    unsigned short* h1 = (unsigned short*)p; p += (size_t)PADROWS * 2048 * 2;
    unsigned short* h2 = (unsigned short*)p; p += (size_t)PADROWS * 2048 * 2;
    unsigned short* zb = (unsigned short*)p; p += (size_t)PADROWS * 256 * 2;
    unsigned short* tw1  = (unsigned short*)p; p += (size_t)8 * 2048 * 1024 * 2;
    unsigned short* tw2  = (unsigned short*)p; p += (size_t)8 * 2048 * 2048 * 2;
    unsigned short* tw3  = (unsigned short*)p; p += (size_t)8 * 2048 * 2048 * 2;
    unsigned short* tw4  = (unsigned short*)p; p += (size_t)8 * 512 * 2048 * 2;
    unsigned short* tds1 = (unsigned short*)p; p += (size_t)2048 * 256 * 2;
    unsigned short* tds2 = (unsigned short*)p; p += (size_t)2048 * 2048 * 2;
    unsigned short* thd1 = (unsigned short*)p; p += (size_t)8 * 2048 * 2048 * 2;
    unsigned short* thd2 = (unsigned short*)p; p += (size_t)8 * 1024 * 2048 * 2;
    float* scat = out;   // reuse d_out as 8 MB scat scratch; fully overwritten later

    const TP tnone = { nullptr, nullptr, 64, 64, 0 };
    const TP tpW2  = { enc_W2, tw2, 2048, 2048, 8192 };
    const TP tpW3  = { enc_W3, tw3, 2048, 2048, 8192 };
    const TP tpW4  = { enc_W4, tw4, 2048,  512, 2048 };
    const TP tpDS1 = { ds_W1, tds1,  256, 2048,  128 };
    const TP tpDS2 = { ds_W2, tds2, 2048, 2048, 1024 };
    const TP tpHD1 = { hd_W1, thd1, 2048, 2048, 8192 };
    const TP tpHD2 = { hd_W2, thd2, 2048, 1024, 4096 };

    setup_kernel<<<1, 1024, 0, stream>>>(task, perm, offs, table128, table256);
    permute_cast_kernel<<<B_ROWS, 256, 0, stream>>>(x, perm, xp);

    // enc_W1 must be ready before the first GEMM -> standalone transpose
    transpose_cast_kernel<<<dim3(16, 32, 8), 256, 0, stream>>>(enc_W1, tw1, 1024, 2048);

    // All gridDim.x and GX are %8==0 (XCD remap validity).
    // D1: enc1 8-phase (GX=24, y=8) + transpose enc_W2 (8192 tiles / (8*2) = 512) -> 536
    gemm8p_kernel<0><<<dim3(536, 8), 512, 0, stream>>>(xp, tw1, enc_b1, h1, offs, table256, nullptr, 1024, 2048, 2048, B_ROWS, MAXT256, tpW2, tnone);
    // D2: enc2 8-phase + transpose enc_W3 -> 536
    gemm8p_kernel<0><<<dim3(536, 8), 512, 0, stream>>>(h1, tw2, enc_b2, h2, offs, table256, nullptr, 2048, 2048, 2048, B_ROWS, MAXT256, tpW3, tnone);
    // D3: enc3 8-phase + transpose enc_W4+ds_W1 (2176/(16) = 136) -> 160
    gemm8p_kernel<0><<<dim3(160, 8), 512, 0, stream>>>(h2, tw3, enc_b3, h1, offs, table256, nullptr, 2048, 2048, 2048, B_ROWS, MAXT256, tpW4, tpDS1);
    // D4: enc4 gemm12<1,64> (N=512, y=8) + transpose ds_W2 (1024/8 = 128) -> 168
    gemm12_kernel<1, 64><<<dim3(168, 8), 256, 0, stream>>>(h1, tw4, enc_b4, scat, offs, table128, nullptr, 2048, 512, 512, B_ROWS, MAXT128, tpDS2, tnone);

    vae_kernel<<<B_ROWS, 256, 0, stream>>>(scat, eps, perm, zb);

    // D5: ds1 gemm12<0,128> (ungrouped GX=32, K=256, y=16) + transpose hd_W1 (8192/16=512) -> 544
    gemm12_kernel<0, 128><<<dim3(544, 16), 256, 0, stream>>>(zb, tds1, ds_b1, h2, nullptr, nullptr, nullptr, 256, 2048, 2048, B_ROWS, 32, tpHD1, tnone);
    // D6: ds2 8-phase (ungrouped GX=16, y=8) + transpose hd_W2 (4096/16=256) -> 272
    gemm8p_kernel<0><<<dim3(272, 8), 512, 0, stream>>>(h2, tds2, ds_b2, h1, nullptr, nullptr, nullptr, 2048, 2048, 2048, B_ROWS, 16, tpHD2, tnone);

    // D7: hd1 8-phase (grouped, pure) -> 24
    gemm8p_kernel<0><<<dim3(24, 8), 512, 0, stream>>>(h1, thd1, hd_b1, h2, offs, table256, nullptr, 2048, 2048, 2048, B_ROWS, MAXT256, tnone, tnone);
    // D8: hd2 gemm12<2,64> (grouped, sigmoid scatter, N=1024, y=16) -> 40
    gemm12_kernel<2, 64><<<dim3(MAXT128, 16), 256, 0, stream>>>(h2, thd2, hd_b2, out, offs, table128, perm, 2048, 1024, 1024, B_ROWS, MAXT128, tnone, tnone);
}

// Round 17
// 617.420 us; speedup vs baseline: 1.5258x; 1.1772x over previous
//
#include <hip/hip_runtime.h>
#include <hip/hip_bf16.h>

#define T_TASKS 8
#define B_ROWS 4096
#define PADROWS 4224      // +128 so partial-tile A loads stay in-bounds
#define BM 128
#define BK 32
#define MAXTILES 40       // sum over tasks of ceil(cnt/BM) <= T + B/BM = 40

typedef __attribute__((ext_vector_type(4))) float f32x4;
typedef __attribute__((ext_vector_type(8))) short bf16x8;

#define GLOAD_LDS16(g, l) __builtin_amdgcn_global_load_lds( \
    (const __attribute__((address_space(1))) void*)(g), \
    (__attribute__((address_space(3))) void*)(l), 16, 0, 0)

struct TP { const float* src; unsigned short* dst; int K; int N; int ntiles; };

__device__ __forceinline__ unsigned short f32_to_bf16(float f) {
    union { float f; unsigned int u; } v; v.f = f;
    unsigned int r = v.u + 0x7FFF + ((v.u >> 16) & 1);  // RNE
    return (unsigned short)(r >> 16);
}

// ---------------- setup: counting sort by task + tile table ----------------
__global__ void setup_kernel(const int* __restrict__ task, int* __restrict__ perm,
                             int* __restrict__ offs, int* __restrict__ table) {
    __shared__ int cnt[T_TASKS];
    __shared__ int cur[T_TASKS];
    int tid = threadIdx.x;
    if (tid < T_TASKS) cnt[tid] = 0;
    __syncthreads();
    for (int b = tid; b < B_ROWS; b += blockDim.x)
        atomicAdd(&cnt[task[b]], 1);
    __syncthreads();
    if (tid == 0) {
        int o = 0;
        for (int t = 0; t < T_TASKS; ++t) { offs[t] = o; cur[t] = o; o += cnt[t]; }
        offs[T_TASKS] = o;
        int s = 0;
        for (int t = 0; t < T_TASKS; ++t) {
            int nt = (cnt[t] + BM - 1) / BM;
            for (int j = 0; j < nt; ++j) table[s++] = (t << 16) | j;
        }
        for (; s < MAXTILES; ++s) table[s] = -1;
    }
    __syncthreads();
    for (int b = tid; b < B_ROWS; b += blockDim.x) {
        int t = task[b];
        int pos = atomicAdd(&cur[t], 1);
        perm[pos] = b;
    }
}

// ---------------- permute + cast x -> bf16 ----------------
__global__ void permute_cast_kernel(const float* __restrict__ x, const int* __restrict__ perm,
                                    unsigned short* __restrict__ xp) {
    int rowp = blockIdx.x;
    int src = perm[rowp];
    const float4* xin = reinterpret_cast<const float4*>(x + (size_t)src * 1024);
    unsigned short* dst = xp + (size_t)rowp * 1024;
    int c4 = threadIdx.x;
    float4 v = xin[c4];
    ushort4 o;
    o.x = f32_to_bf16(v.x); o.y = f32_to_bf16(v.y);
    o.z = f32_to_bf16(v.z); o.w = f32_to_bf16(v.w);
    *reinterpret_cast<ushort4*>(dst + c4 * 4) = o;
}

// ---------------- VAE reparameterization ----------------
__global__ void vae_kernel(const float* __restrict__ scat, const float* __restrict__ eps,
                           const int* __restrict__ perm, unsigned short* __restrict__ z) {
    int rowp = blockIdx.x;
    int c = threadIdx.x;
    int src = perm[rowp];
    float mu = scat[(size_t)rowp * 512 + c];
    float ls = scat[(size_t)rowp * 512 + 256 + c];
    float e  = eps[(size_t)src * 256 + c];
    z[(size_t)rowp * 256 + c] = f32_to_bf16(mu + __expf(ls) * e);
}

// ---------------- standalone weight transpose (enc_W1 only) ----------------
__global__ __launch_bounds__(256)
void transpose_cast_kernel(const float* __restrict__ W, unsigned short* __restrict__ Wt,
                           int K, int N) {
    const size_t toff = (size_t)blockIdx.z * K * N;
    const float* Ws = W + toff;
    unsigned short* Wd = Wt + toff;
    const int k0 = blockIdx.x * 64;
    const int n0 = blockIdx.y * 64;
    __shared__ unsigned short Tt[64 * 64];
    const int tid = threadIdx.x;
    const int n = tid & 63;
    const int kq = tid >> 6;
    #pragma unroll
    for (int i = 0; i < 4; ++i) {
        int kk = kq * 16 + i * 4;
        const float* p = Ws + (size_t)(k0 + kk) * N + n0 + n;
        float v0 = p[0];
        float v1 = p[(size_t)N];
        float v2 = p[(size_t)2 * N];
        float v3 = p[(size_t)3 * N];
        unsigned int lo = (unsigned int)f32_to_bf16(v0) | ((unsigned int)f32_to_bf16(v1) << 16);
        unsigned int hi = (unsigned int)f32_to_bf16(v2) | ((unsigned int)f32_to_bf16(v3) << 16);
        int c = (kk >> 2) ^ (n & 15);
        *reinterpret_cast<uint2*>(Tt + n * 64 + c * 4) = make_uint2(lo, hi);
    }
    __syncthreads();
    #pragma unroll
    for (int it = 0; it < 2; ++it) {
        int c  = it * 256 + tid;
        int nn = c >> 3;
        int cg = c & 7;
        int c1 = (cg * 2) ^ (nn & 15);
        int c2 = (cg * 2 + 1) ^ (nn & 15);
        uint2 a = *reinterpret_cast<const uint2*>(Tt + nn * 64 + c1 * 4);
        uint2 b = *reinterpret_cast<const uint2*>(Tt + nn * 64 + c2 * 4);
        uint4 o = make_uint4(a.x, a.y, b.x, b.y);
        *reinterpret_cast<uint4*>(Wd + (size_t)(n0 + nn) * K + k0 + cg * 8) = o;
    }
}

// ---------------- fused grouped GEMM (templated BN) + transpose-role blocks ----------------
// Consolidation of all per-knob winners (R12, measured best = 618 us):
//   BN=128 (R11: fewest serial steps/CU) or BN=64 for small-N layers (grid size);
//   B: bf16 pre-transposed [t][N][K] via global_load_lds (R4/R6: 3-4 VMEM/step, no cvt burst);
//   ride-along transposes (R4/R6), XCD-chunked bx remap (R6), R6 swizzle (~0 conflicts).
// GEMM (bx < GX); transpose role (bx >= GX): up to two weight tensors, 64x64 tiles.
// MODE 0: relu -> bf16; MODE 1: f32 store; MODE 2: sigmoid -> f32 scatter via perm
template<int MODE, int BN>
__global__ __launch_bounds__(256, (BN == 64 ? 6 : 4))
void gemm12_kernel(const unsigned short* __restrict__ A,
                   const unsigned short* __restrict__ Wt,
                   const float* __restrict__ bias, void* __restrict__ dst,
                   const int* __restrict__ offs, const int* __restrict__ table,
                   const int* __restrict__ perm,
                   int K, int N, int ldd, int Btot, int GX, TP tpa, TP tpb)
{
    constexpr int NR = BN / 32;                 // acc cols per wave (2 or 4)
    __shared__ unsigned short As[2][BM * BK];   // 8 KB each
    __shared__ unsigned short Bs[2][BN * BK];   // 4/8 KB each (24/32 KB total)

    const int bxh = blockIdx.x;
    const int tid = threadIdx.x;

    if (bxh >= GX) {
        // ---------- transpose role ----------
        int tile = (bxh - GX) * gridDim.y + blockIdx.y;
        const float* src; unsigned short* dstp; int tK, tN;
        if (tile < tpa.ntiles) { src = tpa.src; dstp = tpa.dst; tK = tpa.K; tN = tpa.N; }
        else {
            tile -= tpa.ntiles;
            if (tile >= tpb.ntiles) return;
            src = tpb.src; dstp = tpb.dst; tK = tpb.K; tN = tpb.N;
        }
        int tk = tK >> 6, tn = tN >> 6;
        int z = tile / (tk * tn);
        int r = tile % (tk * tn);
        int k0 = (r % tk) * 64, n0 = (r / tk) * 64;
        const size_t toff = (size_t)z * tK * tN;
        const float* Ws = src + toff;
        unsigned short* Wd = dstp + toff;
        unsigned short* Tt = &As[0][0];
        const int n = tid & 63;
        const int kq = tid >> 6;
        #pragma unroll
        for (int i = 0; i < 4; ++i) {
            int kk = kq * 16 + i * 4;
            const float* p = Ws + (size_t)(k0 + kk) * tN + n0 + n;
            float v0 = p[0];
            float v1 = p[(size_t)tN];
            float v2 = p[(size_t)2 * tN];
            float v3 = p[(size_t)3 * tN];
            unsigned int lo = (unsigned int)f32_to_bf16(v0) | ((unsigned int)f32_to_bf16(v1) << 16);
            unsigned int hi = (unsigned int)f32_to_bf16(v2) | ((unsigned int)f32_to_bf16(v3) << 16);
            int c = (kk >> 2) ^ (n & 15);
            *reinterpret_cast<uint2*>(Tt + n * 64 + c * 4) = make_uint2(lo, hi);
        }
        __syncthreads();
        #pragma unroll
        for (int it = 0; it < 2; ++it) {
            int c  = it * 256 + tid;
            int nn = c >> 3;
            int cg = c & 7;
            int c1 = (cg * 2) ^ (nn & 15);
            int c2 = (cg * 2 + 1) ^ (nn & 15);
            uint2 a = *reinterpret_cast<const uint2*>(Tt + nn * 64 + c1 * 4);
            uint2 b = *reinterpret_cast<const uint2*>(Tt + nn * 64 + c2 * 4);
            uint4 o = make_uint4(a.x, a.y, b.x, b.y);
            *reinterpret_cast<uint4*>(Wd + (size_t)(n0 + nn) * tK + k0 + cg * 8) = o;
        }
        return;
    }

    // ---------- GEMM role ----------
    // XCD-chunked bijective bx remap (GX%8==0 and gridDim.x%8==0 in all launches)
    int bx = (bxh & 7) * (GX >> 3) + (bxh >> 3);

    int t, mtile, off, cnt;
    if (table != nullptr) {
        int v = table[bx];
        if (v < 0) return;
        t = v >> 16; mtile = v & 0xFFFF;
        off = offs[t]; cnt = offs[t + 1] - off;
    } else {
        t = 0; mtile = bx; off = 0; cnt = Btot;
    }
    const int n0 = blockIdx.y * BN;

    const int lane = tid & 63;
    const int wave = tid >> 6;
    const int wr = wave >> 1, wc = wave & 1;

    // staging geometry: lane -> row rl=lane>>2 within a 16-row line, chunk lane&3,
    // source chunk XOR ((rl>>1)&3). LDS dest linear.  (R6-proven)
    const int rl   = lane >> 2;                 // 0..15
    const int csrc = ((lane & 3) ^ ((rl >> 1) & 3)) * 8;
    const unsigned short* Ab = A + ((size_t)(off + mtile * BM + rl)) * K + csrc;
    const unsigned short* Bb = Wt + ((size_t)t * N + n0 + rl) * K + csrc;

    auto stage = [&](int buf, int k0) {
        #pragma unroll
        for (int jj = 0; jj < 2; ++jj) {
            int j = wave * 2 + jj;              // 0..7: A 16-row line
            GLOAD_LDS16(Ab + (size_t)(j * 16) * K + k0, &As[buf][j * 512]);
        }
        #pragma unroll
        for (int jb = 0; jb < BN / 64; ++jb) {
            int j = wave * (BN / 64) + jb;      // B 16-row line
            GLOAD_LDS16(Bb + (size_t)(j * 16) * K + k0, &Bs[buf][j * 512]);
        }
    };

    f32x4 acc[4][NR];
    #pragma unroll
    for (int m = 0; m < 4; ++m)
        #pragma unroll
        for (int n = 0; n < NR; ++n)
            acc[m][n] = (f32x4){0.f, 0.f, 0.f, 0.f};

    auto compute = [&](int buf) {
        bf16x8 af[4], bfr[NR];
        #pragma unroll
        for (int m = 0; m < 4; ++m) {
            int rf = wr * 64 + m * 16 + (lane & 15);
            af[m] = *reinterpret_cast<const bf16x8*>(
                &As[buf][rf * 32 + (((lane >> 4) ^ ((rf >> 1) & 3)) * 8)]);
        }
        #pragma unroll
        for (int n = 0; n < NR; ++n) {
            int nf = wc * (BN / 2) + n * 16 + (lane & 15);
            bfr[n] = *reinterpret_cast<const bf16x8*>(
                &Bs[buf][nf * 32 + (((lane >> 4) ^ ((nf >> 1) & 3)) * 8)]);
        }
        #pragma unroll
        for (int m = 0; m < 4; ++m)
            #pragma unroll
            for (int n = 0; n < NR; ++n)
                acc[m][n] = __builtin_amdgcn_mfma_f32_16x16x32_bf16(af[m], bfr[n], acc[m][n], 0, 0, 0);
    };

    const int nsteps = K / BK;
    stage(0, 0);
    __syncthreads();
    int cur = 0;
    for (int s = 0; s < nsteps; ++s) {
        if (s + 1 < nsteps) stage(cur ^ 1, (s + 1) * BK);   // issue-early: hides under compute
        compute(cur);
        __syncthreads();                                    // drains stage(next) + frag reads
        cur ^= 1;
    }

    // ---- epilogue ----
    const float* bt = bias + (size_t)t * N;
    #pragma unroll
    for (int n = 0; n < NR; ++n) {
        int col = n0 + wc * (BN / 2) + n * 16 + (lane & 15);
        float bv = bt[col];
        #pragma unroll
        for (int m = 0; m < 4; ++m) {
            int rbase = mtile * BM + wr * 64 + m * 16 + ((lane >> 4) << 2);
            #pragma unroll
            for (int j = 0; j < 4; ++j) {
                int local = rbase + j;
                if (local >= cnt) continue;
                float v = acc[m][n][j] + bv;
                if (MODE == 0) {
                    ((unsigned short*)dst)[(size_t)(off + local) * ldd + col] =
                        f32_to_bf16(fmaxf(v, 0.f));
                } else if (MODE == 1) {
                    ((float*)dst)[(size_t)(off + local) * ldd + col] = v;
                } else {
                    int grow = perm[off + local];
                    ((float*)dst)[(size_t)grow * ldd + col] = 1.f / (1.f + __expf(-v));
                }
            }
        }
    }
}

extern "C" void kernel_launch(void* const* d_in, const int* in_sizes, int n_in,
                              void* d_out, int out_size, void* d_ws, size_t ws_size,
                              hipStream_t stream) {
    const float* x      = (const float*)d_in[0];
    const int*   task   = (const int*)d_in[1];
    const float* eps    = (const float*)d_in[2];
    const float* enc_W1 = (const float*)d_in[3];
    const float* enc_b1 = (const float*)d_in[4];
    const float* enc_W2 = (const float*)d_in[5];
    const float* enc_b2 = (const float*)d_in[6];
    const float* enc_W3 = (const float*)d_in[7];
    const float* enc_b3 = (const float*)d_in[8];
    const float* enc_W4 = (const float*)d_in[9];
    const float* enc_b4 = (const float*)d_in[10];
    const float* ds_W1  = (const float*)d_in[11];
    const float* ds_b1  = (const float*)d_in[12];
    const float* ds_W2  = (const float*)d_in[13];
    const float* ds_b2  = (const float*)d_in[14];
    const float* hd_W1  = (const float*)d_in[15];
    const float* hd_b1  = (const float*)d_in[16];
    const float* hd_W2  = (const float*)d_in[17];
    const float* hd_b2  = (const float*)d_in[18];
    float* out = (float*)d_out;

    // ---- workspace layout (~365 MB) ----
    char* ws = (char*)d_ws;
    int* perm  = (int*)ws;
    int* offs  = (int*)(ws + 16384);
    int* table = (int*)(ws + 16384 + 256);
    char* p = ws + 32768;
    unsigned short* xp = (unsigned short*)p; p += (size_t)PADROWS * 1024 * 2;
    unsigned short* h1 = (unsigned short*)p; p += (size_t)PADROWS * 2048 * 2;
    unsigned short* h2 = (unsigned short*)p; p += (size_t)PADROWS * 2048 * 2;
    unsigned short* zb = (unsigned short*)p; p += (size_t)PADROWS * 256 * 2;
    unsigned short* tw1  = (unsigned short*)p; p += (size_t)8 * 2048 * 1024 * 2;
    unsigned short* tw2  = (unsigned short*)p; p += (size_t)8 * 2048 * 2048 * 2;
    unsigned short* tw3  = (unsigned short*)p; p += (size_t)8 * 2048 * 2048 * 2;
    unsigned short* tw4  = (unsigned short*)p; p += (size_t)8 * 512 * 2048 * 2;
    unsigned short* tds1 = (unsigned short*)p; p += (size_t)2048 * 256 * 2;
    unsigned short* tds2 = (unsigned short*)p; p += (size_t)2048 * 2048 * 2;
    unsigned short* thd1 = (unsigned short*)p; p += (size_t)8 * 2048 * 2048 * 2;
    unsigned short* thd2 = (unsigned short*)p; p += (size_t)8 * 1024 * 2048 * 2;
    float* scat = out;   // reuse d_out as 8 MB scat scratch; fully overwritten later

    const TP tnone = { nullptr, nullptr, 64, 64, 0 };
    const TP tpW2  = { enc_W2, tw2, 2048, 2048, 8192 };
    const TP tpW3  = { enc_W3, tw3, 2048, 2048, 8192 };
    const TP tpW4  = { enc_W4, tw4, 2048,  512, 2048 };
    const TP tpDS1 = { ds_W1, tds1,  256, 2048,  128 };
    const TP tpDS2 = { ds_W2, tds2, 2048, 2048, 1024 };
    const TP tpHD1 = { hd_W1, thd1, 2048, 2048, 8192 };
    const TP tpHD2 = { hd_W2, thd2, 2048, 1024, 4096 };

    setup_kernel<<<1, 1024, 0, stream>>>(task, perm, offs, table);
    permute_cast_kernel<<<B_ROWS, 256, 0, stream>>>(x, perm, xp);

    // enc_W1 must be ready before the first GEMM -> standalone transpose
    transpose_cast_kernel<<<dim3(16, 32, 8), 256, 0, stream>>>(enc_W1, tw1, 1024, 2048);

    // All gridDim.x %8==0 (XCD remap validity).
    // D1: enc1 (BN128, y16) + transpose enc_W2 (8192/16=512) -> 552
    gemm12_kernel<0, 128><<<dim3(552, 16), 256, 0, stream>>>(xp, tw1, enc_b1, h1, offs, table, nullptr, 1024, 2048, 2048, B_ROWS, MAXTILES, tpW2, tnone);
    // D2: enc2 + transpose enc_W3 -> 552
    gemm12_kernel<0, 128><<<dim3(552, 16), 256, 0, stream>>>(h1, tw2, enc_b2, h2, offs, table, nullptr, 2048, 2048, 2048, B_ROWS, MAXTILES, tpW3, tnone);
    // D3: enc3 + transpose enc_W4 (2048) + ds_W1 (128): 2176/16=136 -> 176
    gemm12_kernel<0, 128><<<dim3(176, 16), 256, 0, stream>>>(h2, tw3, enc_b3, h1, offs, table, nullptr, 2048, 2048, 2048, B_ROWS, MAXTILES, tpW4, tpDS1);
    // D4: enc4 (BN64, N=512, y8) + transpose ds_W2 (1024/8=128) -> 168
    gemm12_kernel<1, 64><<<dim3(168, 8), 256, 0, stream>>>(h1, tw4, enc_b4, scat, offs, table, nullptr, 2048, 512, 512, B_ROWS, MAXTILES, tpDS2, tnone);

    vae_kernel<<<B_ROWS, 256, 0, stream>>>(scat, eps, perm, zb);

    // D5: ds1 (ungrouped GX=32, K=256, BN128, y16) + transpose hd_W1 (8192/16=512) -> 544
    gemm12_kernel<0, 128><<<dim3(544, 16), 256, 0, stream>>>(zb, tds1, ds_b1, h2, nullptr, nullptr, nullptr, 256, 2048, 2048, B_ROWS, 32, tpHD1, tnone);
    // D6: ds2 (ungrouped) + transpose hd_W2 (4096/16=256) -> 288
    gemm12_kernel<0, 128><<<dim3(288, 16), 256, 0, stream>>>(h2, tds2, ds_b2, h1, nullptr, nullptr, nullptr, 2048, 2048, 2048, B_ROWS, 32, tpHD2, tnone);

    // D7: hd1 (grouped, pure)
    gemm12_kernel<0, 128><<<dim3(MAXTILES, 16), 256, 0, stream>>>(h1, thd1, hd_b1, h2, offs, table, nullptr, 2048, 2048, 2048, B_ROWS, MAXTILES, tnone, tnone);
    // D8: hd2 (grouped, sigmoid scatter, BN64, y16) -> 40
    gemm12_kernel<2, 64><<<dim3(MAXTILES, 16), 256, 0, stream>>>(h2, thd2, hd_b2, out, offs, table, perm, 2048, 1024, 1024, B_ROWS, MAXTILES, tnone, tnone);
}